// Round 3
// baseline (1046.999 us; speedup 1.0000x reference)
//
#include <hip/hip_runtime.h>
#include <hip/hip_bf16.h>
#include <stdint.h>

using bf16 = __hip_bfloat16;
typedef __bf16 bf16x8 __attribute__((ext_vector_type(8)));
typedef float  f32x4  __attribute__((ext_vector_type(4)));

#define TOKENS 16384
#define DMODEL 1024
#define DFF    4096

// ---------------------------------------------------------------------------
// async global->LDS, 16B per lane. LDS dest = wave-uniform base + lane*16,
// so the LDS layout must be contiguous in lane order (no padding).
// ---------------------------------------------------------------------------
__device__ __forceinline__ void gload_lds16(const void* gptr, void* lptr) {
  __builtin_amdgcn_global_load_lds(
      (const __attribute__((address_space(1))) uint32_t*)gptr,
      (__attribute__((address_space(3))) uint32_t*)lptr,
      16, 0, 0);
}

__device__ __forceinline__ float bfraw2f(unsigned short u) {
  union { unsigned int i; float f; } x;
  x.i = ((unsigned int)u) << 16;
  return x.f;
}

// ---------------------------------------------------------------------------
// f32 -> bf16 elementwise convert (x). One float4 per thread.
// ---------------------------------------------------------------------------
__global__ __launch_bounds__(256) void cvt_f32_bf16(
    const float* __restrict__ in, bf16* __restrict__ out, int n4) {
  const int i = blockIdx.x * 256 + threadIdx.x;
  if (i >= n4) return;
  const float4 v = reinterpret_cast<const float4*>(in)[i];
  bf16 o[4] = {__float2bfloat16(v.x), __float2bfloat16(v.y),
               __float2bfloat16(v.z), __float2bfloat16(v.w)};
  reinterpret_cast<uint2*>(out)[i] = *reinterpret_cast<const uint2*>(o);
}

// ---------------------------------------------------------------------------
// Tiled transpose + convert: in[R][C] (f32) -> out[C][R] (bf16).
// ---------------------------------------------------------------------------
__global__ __launch_bounds__(256) void transpose_f32_bf16(
    const float* __restrict__ in, bf16* __restrict__ out, int R, int C) {
  __shared__ float tile[32][33];
  const int bx = blockIdx.x * 32;  // col base of input
  const int by = blockIdx.y * 32;  // row base of input
  const int tx = threadIdx.x;      // 0..31
  const int ty = threadIdx.y;      // 0..7
#pragma unroll
  for (int i = 0; i < 32; i += 8)
    tile[ty + i][tx] = in[(size_t)(by + ty + i) * C + (bx + tx)];
  __syncthreads();
#pragma unroll
  for (int i = 0; i < 32; i += 8)
    out[(size_t)(bx + ty + i) * R + (by + tx)] =
        __float2bfloat16(tile[tx][ty + i]);
}

// ---------------------------------------------------------------------------
// GEMM: C[M,N] = A[M,K] * B[K,N], A row-major bf16, Bt = B^T [N,K] bf16.
// 128x128 tile, BK=32, 4 waves in 2x2, each wave 4x4 mfma_f32_16x16x32_bf16.
// epi: 0 = +bias                  -> bf16 out
//      1 = +bias, relu            -> bf16 out
//      2 = +bias + resf (f32)     -> bf16 out
//      3 = +bias + resb (bf16)    -> bf16 out
// ---------------------------------------------------------------------------
__global__ __launch_bounds__(256) void gemm_bt(
    const bf16* __restrict__ A, const bf16* __restrict__ Bt,
    const float* __restrict__ bias, const float* __restrict__ resf,
    const bf16* __restrict__ resb, bf16* __restrict__ outb,
    const int M, const int N, const int K, const int epi) {
  __shared__ alignas(16) bf16 As[128 * 32];
  __shared__ alignas(16) bf16 Bs[128 * 32];

  const int t    = threadIdx.x;
  const int wave = t >> 6;
  const int lane = t & 63;
  const int m_base = blockIdx.y * 128;
  const int n_base = blockIdx.x * 128;
  const int wm = (wave >> 1) * 64;
  const int wn = (wave & 1) * 64;

  // staging: thread t loads 16B (8 bf16): row = t>>2 (+64), kchunk = (t&3)*8.
  // LDS offset = t*16 bytes => wave-uniform base + lane*16. (lane-ordered)
  const int sr = t >> 2;
  const int sk = (t & 3) * 8;
  const bf16* aptr0 = A  + (size_t)(m_base + sr) * K + sk;
  const bf16* aptr1 = aptr0 + (size_t)64 * K;
  const bf16* bptr0 = Bt + (size_t)(n_base + sr) * K + sk;
  const bf16* bptr1 = bptr0 + (size_t)64 * K;
  bf16* as0 = &As[sr * 32 + sk];
  bf16* as1 = &As[(sr + 64) * 32 + sk];
  bf16* bs0 = &Bs[sr * 32 + sk];
  bf16* bs1 = &Bs[(sr + 64) * 32 + sk];

  const int lr = lane & 15;        // A row / Bt row within 16-tile
  const int lk = (lane >> 4) * 8;  // k offset within BK=32

  f32x4 acc[4][4] = {};

  for (int k0 = 0; k0 < K; k0 += 32) {
    gload_lds16(aptr0 + k0, as0);
    gload_lds16(aptr1 + k0, as1);
    gload_lds16(bptr0 + k0, bs0);
    gload_lds16(bptr1 + k0, bs1);
    __syncthreads();  // drains vmcnt -> LDS valid

    bf16x8 af[4], bfv[4];
#pragma unroll
    for (int i = 0; i < 4; ++i) {
      af[i]  = *reinterpret_cast<const bf16x8*>(&As[(wm + i * 16 + lr) * 32 + lk]);
      bfv[i] = *reinterpret_cast<const bf16x8*>(&Bs[(wn + i * 16 + lr) * 32 + lk]);
    }
#pragma unroll
    for (int mi = 0; mi < 4; ++mi)
#pragma unroll
      for (int ni = 0; ni < 4; ++ni)
        acc[mi][ni] = __builtin_amdgcn_mfma_f32_16x16x32_bf16(
            af[mi], bfv[ni], acc[mi][ni], 0, 0, 0);
    __syncthreads();  // protect LDS from next iteration's staging
  }

  // C/D layout: col = lane&15, row = (lane>>4)*4 + reg  [verified m89/m91]
  const int or0 = (lane >> 4) * 4;
  const int oc  = lane & 15;
#pragma unroll
  for (int ni = 0; ni < 4; ++ni) {
    const int col = n_base + wn + ni * 16 + oc;
    const float bv = bias[col];
#pragma unroll
    for (int mi = 0; mi < 4; ++mi) {
      const int row0 = m_base + wm + mi * 16 + or0;
#pragma unroll
      for (int r = 0; r < 4; ++r) {
        const size_t idx = (size_t)(row0 + r) * N + col;
        float v0 = acc[mi][ni][r] + bv;
        if (epi == 1) v0 = fmaxf(v0, 0.f);
        else if (epi == 2) v0 += resf[idx];
        else if (epi == 3) v0 += __bfloat162float(resb[idx]);
        outb[idx] = __float2bfloat16(v0);
      }
    }
  }
}

// ---------------------------------------------------------------------------
// Per-token head-mixing attention. qkv row (3072): e = h*192 + which*64 + d,
// which: 0=q 1=k 2=v. scores[h][g] = q_h . k_g / 8, softmax over g,
// ctx[h*64+d] = sum_g p[h][g] * v[g][d].  One 256-thread block per token.
// ---------------------------------------------------------------------------
__global__ __launch_bounds__(256) void attn_kernel(
    const bf16* __restrict__ qkv, bf16* __restrict__ ctx) {
  __shared__ float q[16][65], kk[16][65], vv[16][65];
  __shared__ float sc[16][17], pw[16][17];
  const int tok = blockIdx.x;
  const int t   = threadIdx.x;

  const ushort2* base2 =
      reinterpret_cast<const ushort2*>(qkv + (size_t)tok * 3072);
#pragma unroll
  for (int e2 = t; e2 < 1536; e2 += 256) {
    const ushort2 u = base2[e2];
    const int e = e2 * 2;
    const int h = e / 192;
    const int rem = e - h * 192;
    const int which = rem >> 6;
    const int d = rem & 63;
    const float f0 = bfraw2f(u.x), f1 = bfraw2f(u.y);
    if (which == 0)      { q[h][d] = f0;  q[h][d + 1] = f1; }
    else if (which == 1) { kk[h][d] = f0; kk[h][d + 1] = f1; }
    else                 { vv[h][d] = f0; vv[h][d + 1] = f1; }
  }
  __syncthreads();

  const int h = t >> 4, g = t & 15;
  float s = 0.f;
#pragma unroll
  for (int d = 0; d < 64; ++d) s += q[h][d] * kk[g][d];
  s *= 0.125f;
  sc[h][g] = s;
  __syncthreads();

  float mx = sc[h][0];
#pragma unroll
  for (int j = 1; j < 16; ++j) mx = fmaxf(mx, sc[h][j]);
  float sum = 0.f;
#pragma unroll
  for (int j = 0; j < 16; ++j) sum += __expf(sc[h][j] - mx);
  pw[h][g] = __expf(s - mx) / sum;
  __syncthreads();

  const int d0 = (t & 15) * 4;
  float c0 = 0.f, c1 = 0.f, c2 = 0.f, c3 = 0.f;
#pragma unroll
  for (int j = 0; j < 16; ++j) {
    const float w = pw[h][j];
    c0 += w * vv[j][d0 + 0];
    c1 += w * vv[j][d0 + 1];
    c2 += w * vv[j][d0 + 2];
    c3 += w * vv[j][d0 + 3];
  }
  bf16 o[4] = {__float2bfloat16(c0), __float2bfloat16(c1),
               __float2bfloat16(c2), __float2bfloat16(c3)};
  *reinterpret_cast<uint2*>(ctx + (size_t)tok * 1024 + t * 4) =
      *reinterpret_cast<const uint2*>(o);
}

// ---------------------------------------------------------------------------
// LayerNorm over 1024, bf16 input, f32 gamma/beta.
// outf != nullptr: write f32. else write bf16 to outb.
// One block per row, 256 threads x 4 elements.
// ---------------------------------------------------------------------------
__global__ __launch_bounds__(256) void ln_kernel(
    const bf16* __restrict__ y, const float* __restrict__ gamma,
    const float* __restrict__ beta, bf16* __restrict__ outb,
    float* __restrict__ outf) {
  const int row = blockIdx.x;
  const int t = threadIdx.x;
  const uint2 raw =
      reinterpret_cast<const uint2*>(y + (size_t)row * 1024)[t];
  float f0 = bfraw2f((unsigned short)(raw.x & 0xffff));
  float f1 = bfraw2f((unsigned short)(raw.x >> 16));
  float f2 = bfraw2f((unsigned short)(raw.y & 0xffff));
  float f3 = bfraw2f((unsigned short)(raw.y >> 16));
  float s  = f0 + f1 + f2 + f3;
  float ss = f0 * f0 + f1 * f1 + f2 * f2 + f3 * f3;
#pragma unroll
  for (int off = 32; off > 0; off >>= 1) {
    s  += __shfl_down(s, off);
    ss += __shfl_down(ss, off);
  }
  __shared__ float red[8];
  const int wave = t >> 6, lane = t & 63;
  if (lane == 0) { red[wave] = s; red[wave + 4] = ss; }
  __syncthreads();
  s  = red[0] + red[1] + red[2] + red[3];
  ss = red[4] + red[5] + red[6] + red[7];
  const float mu  = s * (1.0f / 1024.0f);
  const float var = ss * (1.0f / 1024.0f) - mu * mu;
  const float inv = rsqrtf(var + 1e-5f);
  const int c = t * 4;
  const float r0 = (f0 - mu) * inv * gamma[c + 0] + beta[c + 0];
  const float r1 = (f1 - mu) * inv * gamma[c + 1] + beta[c + 1];
  const float r2 = (f2 - mu) * inv * gamma[c + 2] + beta[c + 2];
  const float r3 = (f3 - mu) * inv * gamma[c + 3] + beta[c + 3];
  if (outf != nullptr) {
    float4 o4 = {r0, r1, r2, r3};
    reinterpret_cast<float4*>(outf + (size_t)row * 1024)[t] = o4;
  } else {
    bf16 o[4] = {__float2bfloat16(r0), __float2bfloat16(r1),
                 __float2bfloat16(r2), __float2bfloat16(r3)};
    *reinterpret_cast<uint2*>(outb + (size_t)row * 1024 + c) =
        *reinterpret_cast<const uint2*>(o);
  }
}

// ---------------------------------------------------------------------------
extern "C" void kernel_launch(void* const* d_in, const int* in_sizes, int n_in,
                              void* d_out, int out_size, void* d_ws, size_t ws_size,
                              hipStream_t stream) {
  const float* x    = (const float*)d_in[0];
  const float* Wqkv = (const float*)d_in[1];
  const float* bqkv = (const float*)d_in[2];
  const float* Wo   = (const float*)d_in[3];
  const float* bo   = (const float*)d_in[4];
  const float* W1   = (const float*)d_in[5];
  const float* b1   = (const float*)d_in[6];
  const float* W2   = (const float*)d_in[7];
  const float* b2   = (const float*)d_in[8];
  const float* g1   = (const float*)d_in[9];
  const float* be1  = (const float*)d_in[10];
  const float* g2   = (const float*)d_in[11];
  const float* be2  = (const float*)d_in[12];
  float* out = (float*)d_out;  // reference output dtype is float32

  // Workspace layout (overlays annotated). Total ~226 MB.
  //  A (33.5MB): xb -> ctx -> y2b
  //  B (134.2MB): qkvb(100.7) ++ ybufb(33.5); hbuf = whole region
  //  D (33.5MB): x1b
  //  E (25.2MB): transposed weights
  char* p = (char*)d_ws;
  bf16* regA  = (bf16*)p;  p += (size_t)TOKENS * 1024 * 2;
  bf16* qkvb  = (bf16*)p;  // also start of hbuf
  bf16* hbuf  = qkvb;
  p += (size_t)TOKENS * 3072 * 2;
  bf16* ybufb = (bf16*)p;  p += (size_t)TOKENS * 1024 * 2;
  bf16* x1b   = (bf16*)p;  p += (size_t)TOKENS * 1024 * 2;
  bf16* WqkvT = (bf16*)p;  p += (size_t)3072 * 1024 * 2;
  bf16* WoT   = (bf16*)p;  p += (size_t)1024 * 1024 * 2;
  bf16* W1T   = (bf16*)p;  p += (size_t)4096 * 1024 * 2;
  bf16* W2T   = (bf16*)p;  p += (size_t)1024 * 4096 * 2;

  bf16* xb  = regA;   // x as bf16 (dead after QKV GEMM)
  bf16* ctx = regA;   // attn output (dead after Wo GEMM)
  bf16* y2b = regA;   // FF2 output pre-LN

  // x -> bf16
  cvt_f32_bf16<<<(TOKENS * 1024 / 4 + 255) / 256, 256, 0, stream>>>(
      x, xb, TOKENS * 1024 / 4);

  // weight transposes + convert: W[K][N] f32 -> Wt[N][K] bf16
  const dim3 tb(32, 8);
  transpose_f32_bf16<<<dim3(3072 / 32, 1024 / 32), tb, 0, stream>>>(Wqkv, WqkvT, 1024, 3072);
  transpose_f32_bf16<<<dim3(1024 / 32, 1024 / 32), tb, 0, stream>>>(Wo,   WoT,   1024, 1024);
  transpose_f32_bf16<<<dim3(4096 / 32, 1024 / 32), tb, 0, stream>>>(W1,   W1T,   1024, 4096);
  transpose_f32_bf16<<<dim3(1024 / 32, 4096 / 32), tb, 0, stream>>>(W2,   W2T,   4096, 1024);

  // qkv = x @ Wqkv + bqkv -> bf16
  gemm_bt<<<dim3(3072 / 128, TOKENS / 128), 256, 0, stream>>>(
      xb, WqkvT, bqkv, nullptr, nullptr, qkvb, TOKENS, 3072, 1024, 0);

  // per-token attention -> ctx bf16 (overwrites xb)
  attn_kernel<<<TOKENS, 256, 0, stream>>>(qkvb, ctx);

  // y = ctx @ Wo + bo + x -> bf16 (into ybufb)
  gemm_bt<<<dim3(1024 / 128, TOKENS / 128), 256, 0, stream>>>(
      ctx, WoT, bo, x, nullptr, ybufb, TOKENS, 1024, 1024, 2);

  // x1 = LN(y) -> bf16
  ln_kernel<<<TOKENS, 256, 0, stream>>>(ybufb, g1, be1, x1b, nullptr);

  // h = relu(x1 @ W1 + b1) -> bf16 (overlays qkvb+ybufb, both dead)
  gemm_bt<<<dim3(4096 / 128, TOKENS / 128), 256, 0, stream>>>(
      x1b, W1T, b1, nullptr, nullptr, hbuf, TOKENS, 4096, 1024, 1);

  // y2 = h @ W2 + b2 + x1 -> bf16 (into region A, ctx dead)
  gemm_bt<<<dim3(1024 / 128, TOKENS / 128), 256, 0, stream>>>(
      hbuf, W2T, b2, nullptr, x1b, y2b, TOKENS, 1024, 4096, 3);

  // out = LN(y2) -> f32 (harness output dtype)
  ln_kernel<<<TOKENS, 256, 0, stream>>>(y2b, g2, be2, nullptr, out);
}

// Round 4
// 907.029 us; speedup vs baseline: 1.1543x; 1.1543x over previous
//
#include <hip/hip_runtime.h>
#include <hip/hip_bf16.h>
#include <stdint.h>

using bf16 = __hip_bfloat16;
typedef __bf16 bf16x8 __attribute__((ext_vector_type(8)));
typedef float  f32x4  __attribute__((ext_vector_type(4)));

#define TOKENS 16384
#define DMODEL 1024
#define DFF    4096

// ---------------------------------------------------------------------------
// async global->LDS, 16B per lane. LDS dest = wave-uniform base + lane*16,
// so the LDS layout must be contiguous in lane order (no padding).
// ---------------------------------------------------------------------------
__device__ __forceinline__ void gload_lds16(const void* gptr, void* lptr) {
  __builtin_amdgcn_global_load_lds(
      (const __attribute__((address_space(1))) uint32_t*)gptr,
      (__attribute__((address_space(3))) uint32_t*)lptr,
      16, 0, 0);
}

__device__ __forceinline__ float bfraw2f(unsigned short u) {
  union { unsigned int i; float f; } x;
  x.i = ((unsigned int)u) << 16;
  return x.f;
}

__device__ __forceinline__ unsigned short f2bfraw(float f) {
  union { float f; unsigned int i; } x;
  x.f = f;
  unsigned int lsb = (x.i >> 16) & 1;
  return (unsigned short)((x.i + 0x7fff + lsb) >> 16);  // RNE (finite inputs)
}

// ---------------------------------------------------------------------------
// f32 -> bf16 elementwise convert (x). One float4 per thread.
// ---------------------------------------------------------------------------
__global__ __launch_bounds__(256) void cvt_f32_bf16(
    const float* __restrict__ in, bf16* __restrict__ out, int n4) {
  const int i = blockIdx.x * 256 + threadIdx.x;
  if (i >= n4) return;
  const float4 v = reinterpret_cast<const float4*>(in)[i];
  bf16 o[4] = {__float2bfloat16(v.x), __float2bfloat16(v.y),
               __float2bfloat16(v.z), __float2bfloat16(v.w)};
  reinterpret_cast<uint2*>(out)[i] = *reinterpret_cast<const uint2*>(o);
}

// ---------------------------------------------------------------------------
// Tiled transpose + convert: in[R][C] (f32) -> out[C][R] (bf16).
// ---------------------------------------------------------------------------
__global__ __launch_bounds__(256) void transpose_f32_bf16(
    const float* __restrict__ in, bf16* __restrict__ out, int R, int C) {
  __shared__ float tile[32][33];
  const int bx = blockIdx.x * 32;  // col base of input
  const int by = blockIdx.y * 32;  // row base of input
  const int tx = threadIdx.x;      // 0..31
  const int ty = threadIdx.y;      // 0..7
#pragma unroll
  for (int i = 0; i < 32; i += 8)
    tile[ty + i][tx] = in[(size_t)(by + ty + i) * C + (bx + tx)];
  __syncthreads();
#pragma unroll
  for (int i = 0; i < 32; i += 8)
    out[(size_t)(bx + ty + i) * R + (by + tx)] =
        __float2bfloat16(tile[tx][ty + i]);
}

// ---------------------------------------------------------------------------
// GEMM: C[M,N] = A[M,K] * B[K,N], A row-major bf16, Bt = B^T [N,K] bf16.
// 128x128 tile, BK=32, 4 waves in 2x2, each wave 4x4 mfma_f32_16x16x32_bf16
// with SWAPPED operands: mfma(bfv, af) computes the fragment transposed, so
// each lane holds 4 CONSECUTIVE COLUMNS of one row:
//   row = wm + mi*16 + (lane&15), cols = wn + ni*16 + (lane>>4)*4 + reg.
// Epilogue: bias(+relu) in-register -> bf16x4 packs -> LDS C-tile (stride 136,
// 16B-aligned rows) -> coalesced 16B/lane global stores; residual added in
// the coalesced flush pass.
// epi: 0 = +bias; 1 = +bias,relu; 2 = +bias+resf(f32); 3 = +bias+resb(bf16)
// ---------------------------------------------------------------------------
#define CS_STRIDE 136

__global__ __launch_bounds__(256) void gemm_bt(
    const bf16* __restrict__ A, const bf16* __restrict__ Bt,
    const float* __restrict__ bias, const float* __restrict__ resf,
    const bf16* __restrict__ resb, bf16* __restrict__ outb,
    const int M, const int N, const int K, const int epi) {
  union SMem {
    struct { bf16 As[128 * 32]; bf16 Bs[128 * 32]; } ab;
    bf16 Cs[128 * CS_STRIDE];
  };
  __shared__ alignas(16) SMem sm;

  const int t    = threadIdx.x;
  const int wave = t >> 6;
  const int lane = t & 63;
  const int m_base = blockIdx.y * 128;
  const int n_base = blockIdx.x * 128;
  const int wm = (wave >> 1) * 64;
  const int wn = (wave & 1) * 64;

  // staging: thread t loads 16B (8 bf16): row = t>>2 (+64), kchunk = (t&3)*8.
  // LDS offset = t*16 bytes => wave-uniform base + lane*16. (lane-ordered)
  const int sr = t >> 2;
  const int sk = (t & 3) * 8;
  const bf16* aptr0 = A  + (size_t)(m_base + sr) * K + sk;
  const bf16* aptr1 = aptr0 + (size_t)64 * K;
  const bf16* bptr0 = Bt + (size_t)(n_base + sr) * K + sk;
  const bf16* bptr1 = bptr0 + (size_t)64 * K;
  bf16* as0 = &sm.ab.As[sr * 32 + sk];
  bf16* as1 = &sm.ab.As[(sr + 64) * 32 + sk];
  bf16* bs0 = &sm.ab.Bs[sr * 32 + sk];
  bf16* bs1 = &sm.ab.Bs[(sr + 64) * 32 + sk];

  const int lr = lane & 15;        // A row / Bt row within 16-tile
  const int lk = (lane >> 4) * 8;  // k offset within BK=32

  f32x4 acc[4][4] = {};

  for (int k0 = 0; k0 < K; k0 += 32) {
    gload_lds16(aptr0 + k0, as0);
    gload_lds16(aptr1 + k0, as1);
    gload_lds16(bptr0 + k0, bs0);
    gload_lds16(bptr1 + k0, bs1);
    __syncthreads();  // drains vmcnt -> LDS valid

    bf16x8 af[4], bfv[4];
#pragma unroll
    for (int i = 0; i < 4; ++i) {
      af[i]  = *reinterpret_cast<const bf16x8*>(&sm.ab.As[(wm + i * 16 + lr) * 32 + lk]);
      bfv[i] = *reinterpret_cast<const bf16x8*>(&sm.ab.Bs[(wn + i * 16 + lr) * 32 + lk]);
    }
#pragma unroll
    for (int mi = 0; mi < 4; ++mi)
#pragma unroll
      for (int ni = 0; ni < 4; ++ni)
        acc[mi][ni] = __builtin_amdgcn_mfma_f32_16x16x32_bf16(
            bfv[ni], af[mi], acc[mi][ni], 0, 0, 0);  // swapped -> transposed frag
    __syncthreads();  // protect LDS from next iteration's staging
  }
  // last loop barrier already drained all LDS reads; safe to reuse as Cs.

  // stage C-tile (bias/relu applied) into LDS, 8B per write
  const int g4 = lane >> 4;  // col-quad selector
#pragma unroll
  for (int ni = 0; ni < 4; ++ni) {
    const int cb = wn + ni * 16 + g4 * 4;          // col base within tile
    const float4 bv = *reinterpret_cast<const float4*>(&bias[n_base + cb]);
#pragma unroll
    for (int mi = 0; mi < 4; ++mi) {
      const f32x4 a = acc[mi][ni];
      float v0 = a[0] + bv.x, v1 = a[1] + bv.y;
      float v2 = a[2] + bv.z, v3 = a[3] + bv.w;
      if (epi == 1) {
        v0 = fmaxf(v0, 0.f); v1 = fmaxf(v1, 0.f);
        v2 = fmaxf(v2, 0.f); v3 = fmaxf(v3, 0.f);
      }
      ushort4 pk = {f2bfraw(v0), f2bfraw(v1), f2bfraw(v2), f2bfraw(v3)};
      *reinterpret_cast<ushort4*>(
          &sm.Cs[(wm + mi * 16 + lr) * CS_STRIDE + cb]) = pk;
    }
  }
  __syncthreads();

  // coalesced flush: 16 rows/pass, 16B per lane
  const int fr = t >> 4;        // row within pass
  const int fc = (t & 15) * 8;  // col (8 bf16 = 16B)
#pragma unroll
  for (int pass = 0; pass < 8; ++pass) {
    const int row = pass * 16 + fr;
    const uint4 raw = *reinterpret_cast<const uint4*>(&sm.Cs[row * CS_STRIDE + fc]);
    const size_t gidx = (size_t)(m_base + row) * N + n_base + fc;
    if (epi <= 1) {
      *reinterpret_cast<uint4*>(&outb[gidx]) = raw;
    } else {
      const unsigned short* u = reinterpret_cast<const unsigned short*>(&raw);
      float v[8];
#pragma unroll
      for (int j = 0; j < 8; ++j) v[j] = bfraw2f(u[j]);
      if (epi == 2) {
        const float4 r0 = *reinterpret_cast<const float4*>(&resf[gidx]);
        const float4 r1 = *reinterpret_cast<const float4*>(&resf[gidx + 4]);
        v[0] += r0.x; v[1] += r0.y; v[2] += r0.z; v[3] += r0.w;
        v[4] += r1.x; v[5] += r1.y; v[6] += r1.z; v[7] += r1.w;
      } else {
        const uint4 rb = *reinterpret_cast<const uint4*>(&resb[gidx]);
        const unsigned short* ru = reinterpret_cast<const unsigned short*>(&rb);
#pragma unroll
        for (int j = 0; j < 8; ++j) v[j] += bfraw2f(ru[j]);
      }
      ushort4 lo = {f2bfraw(v[0]), f2bfraw(v[1]), f2bfraw(v[2]), f2bfraw(v[3])};
      ushort4 hi = {f2bfraw(v[4]), f2bfraw(v[5]), f2bfraw(v[6]), f2bfraw(v[7])};
      uint4 o;
      o.x = *reinterpret_cast<const uint32_t*>(&lo.x);
      o.y = *reinterpret_cast<const uint32_t*>(&lo.z);
      o.z = *reinterpret_cast<const uint32_t*>(&hi.x);
      o.w = *reinterpret_cast<const uint32_t*>(&hi.z);
      *reinterpret_cast<uint4*>(&outb[gidx]) = o;
    }
  }
}

// ---------------------------------------------------------------------------
// Per-token head-mixing attention. qkv row (3072): e = h*192 + which*64 + d,
// which: 0=q 1=k 2=v. scores[h][g] = q_h . k_g / 8, softmax over g,
// ctx[h*64+d] = sum_g p[h][g] * v[g][d].  One 256-thread block per token.
// ---------------------------------------------------------------------------
__global__ __launch_bounds__(256) void attn_kernel(
    const bf16* __restrict__ qkv, bf16* __restrict__ ctx) {
  __shared__ float q[16][65], kk[16][65], vv[16][65];
  __shared__ float sc[16][17], pw[16][17];
  const int tok = blockIdx.x;
  const int t   = threadIdx.x;

  const ushort2* base2 =
      reinterpret_cast<const ushort2*>(qkv + (size_t)tok * 3072);
#pragma unroll
  for (int e2 = t; e2 < 1536; e2 += 256) {
    const ushort2 u = base2[e2];
    const int e = e2 * 2;
    const int h = e / 192;
    const int rem = e - h * 192;
    const int which = rem >> 6;
    const int d = rem & 63;
    const float f0 = bfraw2f(u.x), f1 = bfraw2f(u.y);
    if (which == 0)      { q[h][d] = f0;  q[h][d + 1] = f1; }
    else if (which == 1) { kk[h][d] = f0; kk[h][d + 1] = f1; }
    else                 { vv[h][d] = f0; vv[h][d + 1] = f1; }
  }
  __syncthreads();

  const int h = t >> 4, g = t & 15;
  float s = 0.f;
#pragma unroll
  for (int d = 0; d < 64; ++d) s += q[h][d] * kk[g][d];
  s *= 0.125f;
  sc[h][g] = s;
  __syncthreads();

  float mx = sc[h][0];
#pragma unroll
  for (int j = 1; j < 16; ++j) mx = fmaxf(mx, sc[h][j]);
  float sum = 0.f;
#pragma unroll
  for (int j = 0; j < 16; ++j) sum += __expf(sc[h][j] - mx);
  pw[h][g] = __expf(s - mx) / sum;
  __syncthreads();

  const int d0 = (t & 15) * 4;
  float c0 = 0.f, c1 = 0.f, c2 = 0.f, c3 = 0.f;
#pragma unroll
  for (int j = 0; j < 16; ++j) {
    const float w = pw[h][j];
    c0 += w * vv[j][d0 + 0];
    c1 += w * vv[j][d0 + 1];
    c2 += w * vv[j][d0 + 2];
    c3 += w * vv[j][d0 + 3];
  }
  bf16 o[4] = {__float2bfloat16(c0), __float2bfloat16(c1),
               __float2bfloat16(c2), __float2bfloat16(c3)};
  *reinterpret_cast<uint2*>(ctx + (size_t)tok * 1024 + t * 4) =
      *reinterpret_cast<const uint2*>(o);
}

// ---------------------------------------------------------------------------
// LayerNorm over 1024, bf16 input, f32 gamma/beta.
// outf != nullptr: write f32. else write bf16 to outb.
// One block per row, 256 threads x 4 elements.
// ---------------------------------------------------------------------------
__global__ __launch_bounds__(256) void ln_kernel(
    const bf16* __restrict__ y, const float* __restrict__ gamma,
    const float* __restrict__ beta, bf16* __restrict__ outb,
    float* __restrict__ outf) {
  const int row = blockIdx.x;
  const int t = threadIdx.x;
  const uint2 raw =
      reinterpret_cast<const uint2*>(y + (size_t)row * 1024)[t];
  float f0 = bfraw2f((unsigned short)(raw.x & 0xffff));
  float f1 = bfraw2f((unsigned short)(raw.x >> 16));
  float f2 = bfraw2f((unsigned short)(raw.y & 0xffff));
  float f3 = bfraw2f((unsigned short)(raw.y >> 16));
  float s  = f0 + f1 + f2 + f3;
  float ss = f0 * f0 + f1 * f1 + f2 * f2 + f3 * f3;
#pragma unroll
  for (int off = 32; off > 0; off >>= 1) {
    s  += __shfl_down(s, off);
    ss += __shfl_down(ss, off);
  }
  __shared__ float red[8];
  const int wave = t >> 6, lane = t & 63;
  if (lane == 0) { red[wave] = s; red[wave + 4] = ss; }
  __syncthreads();
  s  = red[0] + red[1] + red[2] + red[3];
  ss = red[4] + red[5] + red[6] + red[7];
  const float mu  = s * (1.0f / 1024.0f);
  const float var = ss * (1.0f / 1024.0f) - mu * mu;
  const float inv = rsqrtf(var + 1e-5f);
  const int c = t * 4;
  const float r0 = (f0 - mu) * inv * gamma[c + 0] + beta[c + 0];
  const float r1 = (f1 - mu) * inv * gamma[c + 1] + beta[c + 1];
  const float r2 = (f2 - mu) * inv * gamma[c + 2] + beta[c + 2];
  const float r3 = (f3 - mu) * inv * gamma[c + 3] + beta[c + 3];
  if (outf != nullptr) {
    float4 o4 = {r0, r1, r2, r3};
    reinterpret_cast<float4*>(outf + (size_t)row * 1024)[t] = o4;
  } else {
    bf16 o[4] = {__float2bfloat16(r0), __float2bfloat16(r1),
                 __float2bfloat16(r2), __float2bfloat16(r3)};
    *reinterpret_cast<uint2*>(outb + (size_t)row * 1024 + c) =
        *reinterpret_cast<const uint2*>(o);
  }
}

// ---------------------------------------------------------------------------
extern "C" void kernel_launch(void* const* d_in, const int* in_sizes, int n_in,
                              void* d_out, int out_size, void* d_ws, size_t ws_size,
                              hipStream_t stream) {
  const float* x    = (const float*)d_in[0];
  const float* Wqkv = (const float*)d_in[1];
  const float* bqkv = (const float*)d_in[2];
  const float* Wo   = (const float*)d_in[3];
  const float* bo   = (const float*)d_in[4];
  const float* W1   = (const float*)d_in[5];
  const float* b1   = (const float*)d_in[6];
  const float* W2   = (const float*)d_in[7];
  const float* b2   = (const float*)d_in[8];
  const float* g1   = (const float*)d_in[9];
  const float* be1  = (const float*)d_in[10];
  const float* g2   = (const float*)d_in[11];
  const float* be2  = (const float*)d_in[12];
  float* out = (float*)d_out;  // reference output dtype is float32

  // Workspace layout (overlays annotated). Total ~226 MB.
  //  A (33.5MB): xb -> ctx -> y2b
  //  B (134.2MB): qkvb(100.7) ++ ybufb(33.5); hbuf = whole region
  //  D (33.5MB): x1b
  //  E (25.2MB): transposed weights
  char* p = (char*)d_ws;
  bf16* regA  = (bf16*)p;  p += (size_t)TOKENS * 1024 * 2;
  bf16* qkvb  = (bf16*)p;  // also start of hbuf
  bf16* hbuf  = qkvb;
  p += (size_t)TOKENS * 3072 * 2;
  bf16* ybufb = (bf16*)p;  p += (size_t)TOKENS * 1024 * 2;
  bf16* x1b   = (bf16*)p;  p += (size_t)TOKENS * 1024 * 2;
  bf16* WqkvT = (bf16*)p;  p += (size_t)3072 * 1024 * 2;
  bf16* WoT   = (bf16*)p;  p += (size_t)1024 * 1024 * 2;
  bf16* W1T   = (bf16*)p;  p += (size_t)4096 * 1024 * 2;
  bf16* W2T   = (bf16*)p;  p += (size_t)1024 * 4096 * 2;

  bf16* xb  = regA;   // x as bf16 (dead after QKV GEMM)
  bf16* ctx = regA;   // attn output (dead after Wo GEMM)
  bf16* y2b = regA;   // FF2 output pre-LN

  // x -> bf16
  cvt_f32_bf16<<<(TOKENS * 1024 / 4 + 255) / 256, 256, 0, stream>>>(
      x, xb, TOKENS * 1024 / 4);

  // weight transposes + convert: W[K][N] f32 -> Wt[N][K] bf16
  const dim3 tb(32, 8);
  transpose_f32_bf16<<<dim3(3072 / 32, 1024 / 32), tb, 0, stream>>>(Wqkv, WqkvT, 1024, 3072);
  transpose_f32_bf16<<<dim3(1024 / 32, 1024 / 32), tb, 0, stream>>>(Wo,   WoT,   1024, 1024);
  transpose_f32_bf16<<<dim3(4096 / 32, 1024 / 32), tb, 0, stream>>>(W1,   W1T,   1024, 4096);
  transpose_f32_bf16<<<dim3(1024 / 32, 4096 / 32), tb, 0, stream>>>(W2,   W2T,   4096, 1024);

  // qkv = x @ Wqkv + bqkv -> bf16
  gemm_bt<<<dim3(3072 / 128, TOKENS / 128), 256, 0, stream>>>(
      xb, WqkvT, bqkv, nullptr, nullptr, qkvb, TOKENS, 3072, 1024, 0);

  // per-token attention -> ctx bf16 (overwrites xb)
  attn_kernel<<<TOKENS, 256, 0, stream>>>(qkvb, ctx);

  // y = ctx @ Wo + bo + x -> bf16 (into ybufb)
  gemm_bt<<<dim3(1024 / 128, TOKENS / 128), 256, 0, stream>>>(
      ctx, WoT, bo, x, nullptr, ybufb, TOKENS, 1024, 1024, 2);

  // x1 = LN(y) -> bf16
  ln_kernel<<<TOKENS, 256, 0, stream>>>(ybufb, g1, be1, x1b, nullptr);

  // h = relu(x1 @ W1 + b1) -> bf16 (overlays qkvb+ybufb, both dead)
  gemm_bt<<<dim3(4096 / 128, TOKENS / 128), 256, 0, stream>>>(
      x1b, W1T, b1, nullptr, nullptr, hbuf, TOKENS, 4096, 1024, 1);

  // y2 = h @ W2 + b2 + x1 -> bf16 (into region A, ctx dead)
  gemm_bt<<<dim3(1024 / 128, TOKENS / 128), 256, 0, stream>>>(
      hbuf, W2T, b2, nullptr, x1b, y2b, TOKENS, 1024, 4096, 3);

  // out = LN(y2) -> f32 (harness output dtype)
  ln_kernel<<<TOKENS, 256, 0, stream>>>(y2b, g2, be2, nullptr, out);
}